// Round 1
// baseline (210.831 us; speedup 1.0000x reference)
//
#include <hip/hip_runtime.h>
#include <math.h>

#define DIMS 32
#define NROWS 4096
#define MROWS 8192
#define HID 100
#define TS 128
#define LDK 132  // padded K-major row stride (floats); 132*4=528 B, 16B-aligned

// ---------------- Kernel 1: sum / sumsq of centroids ----------------
__global__ __launch_bounds__(256) void k_var(const float* __restrict__ c,
                                             float* __restrict__ sums) {
    int t = blockIdx.x * 256 + threadIdx.x;  // 64 blocks * 256 threads * 8 floats = 131072
    const float4* c4 = (const float4*)c;
    float4 a = c4[t * 2];
    float4 b = c4[t * 2 + 1];
    float s = a.x + a.y + a.z + a.w + b.x + b.y + b.z + b.w;
    float q = a.x * a.x + a.y * a.y + a.z * a.z + a.w * a.w +
              b.x * b.x + b.y * b.y + b.z * b.z + b.w * b.w;
    #pragma unroll
    for (int off = 32; off > 0; off >>= 1) {
        s += __shfl_down(s, off);
        q += __shfl_down(q, off);
    }
    __shared__ float red[8];
    int lane = threadIdx.x & 63, wid = threadIdx.x >> 6;
    if (lane == 0) { red[wid] = s; red[4 + wid] = q; }
    __syncthreads();
    if (threadIdx.x == 0) {
        float S = red[0] + red[1] + red[2] + red[3];
        float Q = red[4] + red[5] + red[6] + red[7];
        atomicAdd(&sums[0], S);
        atomicAdd(&sums[1], Q);
    }
}

// ---------------- Kernel 2: loc rows + B_n, and A_m ----------------
// blocks 0..15  : loc (4096 rows, 1 thread/row)
// blocks 16..47 : A   (8192 rows, 1 thread/row)
__global__ __launch_bounds__(256) void k_prep(const float* __restrict__ cent,
                                              const float* __restrict__ x,
                                              const float* __restrict__ W1,
                                              const float* __restrict__ W2,
                                              const float* __restrict__ b2,
                                              const float* __restrict__ sums,
                                              float* __restrict__ loc,
                                              float* __restrict__ A,
                                              float* __restrict__ B) {
    const float cnt = (float)(NROWS * DIMS);
    float sum = sums[0], sumsq = sums[1];
    float var = (sumsq - sum * sum / cnt) / (cnt - 1.0f);
    float iv = 1.0f / var;
    const float L2E = 1.44269504088896340736f;

    if (blockIdx.x < 16) {
        __shared__ float w1s[HID * DIMS];
        __shared__ float w2s[DIMS * HID];
        __shared__ float b2s[DIMS];
        for (int i = threadIdx.x; i < HID * DIMS; i += 256) w1s[i] = W1[i];
        for (int i = threadIdx.x; i < DIMS * HID; i += 256) w2s[i] = W2[i];
        if (threadIdx.x < DIMS) b2s[threadIdx.x] = b2[threadIdx.x];
        __syncthreads();

        int n = blockIdx.x * 256 + threadIdx.x;  // 0..4095
        float c[DIMS];
        const float4* cr = (const float4*)(cent + (size_t)n * DIMS);
        #pragma unroll
        for (int i = 0; i < 8; i++) {
            float4 v = cr[i];
            c[4 * i] = v.x; c[4 * i + 1] = v.y; c[4 * i + 2] = v.z; c[4 * i + 3] = v.w;
        }
        float acc[DIMS];
        #pragma unroll
        for (int d = 0; d < DIMS; d++) acc[d] = 0.0f;
        for (int j = 0; j < HID; j++) {
            const float* w = &w1s[j * DIMS];
            float h0 = 0.f, h1 = 0.f, h2 = 0.f, h3 = 0.f;
            #pragma unroll
            for (int d = 0; d < DIMS; d += 4) {
                h0 += c[d] * w[d];
                h1 += c[d + 1] * w[d + 1];
                h2 += c[d + 2] * w[d + 2];
                h3 += c[d + 3] * w[d + 3];
            }
            float h = (h0 + h1) + (h2 + h3);
            #pragma unroll
            for (int d = 0; d < DIMS; d++) acc[d] += h * w2s[d * HID + j];
        }
        float lsq = 0.0f;
        float lrow[DIMS];
        #pragma unroll
        for (int d = 0; d < DIMS; d++) {
            float v = tanhf(acc[d] + b2s[d]) * c[d];
            lrow[d] = v;
            lsq += v * v;
        }
        float4* lo = (float4*)(loc + (size_t)n * DIMS);
        #pragma unroll
        for (int i = 0; i < 8; i++)
            lo[i] = make_float4(lrow[4 * i], lrow[4 * i + 1], lrow[4 * i + 2], lrow[4 * i + 3]);
        B[n] = -0.5f * L2E * lsq * iv;
    } else {
        int m = (blockIdx.x - 16) * 256 + threadIdx.x;  // 0..8191
        const float4* xr = (const float4*)(x + (size_t)m * DIMS);
        float xsq = 0.0f;
        #pragma unroll
        for (int i = 0; i < 8; i++) {
            float4 v = xr[i];
            xsq += v.x * v.x + v.y * v.y + v.z * v.z + v.w * v.w;
        }
        float log_norm = (float)DIMS * logf(2.0f * (float)M_PI * var);
        A[m] = -0.5f * L2E * (xsq * iv + log_norm);
    }
}

// ---------------- Kernel 3: pairwise exp tile ----------------
// out[m,n] = exp2(A_m + B_n + s*dot(loc_n, x_m)),  s = log2(e)/var
// 128x128 tile per block, 256 threads, 8x8 micro-tile.
__global__ __launch_bounds__(256) void k_pair(const float* __restrict__ x,
                                              const float* __restrict__ loc,
                                              const float* __restrict__ A,
                                              const float* __restrict__ B,
                                              const float* __restrict__ sums,
                                              float* __restrict__ out) {
    __shared__ __align__(16) float xs[DIMS][LDK];  // [k][m_local]
    __shared__ __align__(16) float ls[DIMS][LDK];  // [k][n_local]
    __shared__ float As[TS];
    __shared__ float Bs[TS];

    const float cnt = (float)(NROWS * DIMS);
    float sum = sums[0], sumsq = sums[1];
    float var = (sumsq - sum * sum / cnt) / (cnt - 1.0f);
    const float s = 1.44269504088896340736f / var;

    int n0 = blockIdx.x * TS;
    int m0 = blockIdx.y * TS;
    int t = threadIdx.x;

    // Stage tiles, transposing to K-major. Each thread: one half-row (16 floats).
    {
        int ml = t >> 1;               // 0..127
        int kh = (t & 1) * 16;         // 0 or 16
        const float4* xr = (const float4*)(x + (size_t)(m0 + ml) * DIMS + kh);
        float4 v0 = xr[0], v1 = xr[1], v2 = xr[2], v3 = xr[3];
        float vv[16] = {v0.x, v0.y, v0.z, v0.w, v1.x, v1.y, v1.z, v1.w,
                        v2.x, v2.y, v2.z, v2.w, v3.x, v3.y, v3.z, v3.w};
        #pragma unroll
        for (int q = 0; q < 16; q++) xs[kh + q][ml] = vv[q];

        const float4* lr = (const float4*)(loc + (size_t)(n0 + ml) * DIMS + kh);
        float4 u0 = lr[0], u1 = lr[1], u2 = lr[2], u3 = lr[3];
        float uu[16] = {u0.x, u0.y, u0.z, u0.w, u1.x, u1.y, u1.z, u1.w,
                        u2.x, u2.y, u2.z, u2.w, u3.x, u3.y, u3.z, u3.w};
        #pragma unroll
        for (int q = 0; q < 16; q++) ls[kh + q][ml] = uu[q];
    }
    if (t < TS) As[t] = A[m0 + t];
    else        Bs[t - TS] = B[n0 + t - TS];
    __syncthreads();

    int tx = t & 15;   // n groups: n_local = 4*tx+j and 64+4*tx+j
    int ty = t >> 4;   // m groups: m_local = 4*ty+i and 64+4*ty+i

    float acc[8][8];
    #pragma unroll
    for (int i = 0; i < 8; i++)
        #pragma unroll
        for (int j = 0; j < 8; j++) acc[i][j] = 0.0f;

    #pragma unroll 4
    for (int k = 0; k < DIMS; k++) {
        float4 xa = *(const float4*)&xs[k][4 * ty];
        float4 xb = *(const float4*)&xs[k][64 + 4 * ty];
        float4 la = *(const float4*)&ls[k][4 * tx];
        float4 lb = *(const float4*)&ls[k][64 + 4 * tx];
        float xm[8] = {xa.x, xa.y, xa.z, xa.w, xb.x, xb.y, xb.z, xb.w};
        float ln[8] = {la.x, la.y, la.z, la.w, lb.x, lb.y, lb.z, lb.w};
        #pragma unroll
        for (int i = 0; i < 8; i++)
            #pragma unroll
            for (int j = 0; j < 8; j++)
                acc[i][j] += xm[i] * ln[j];
    }

    float ai[8], bj[8];
    #pragma unroll
    for (int i = 0; i < 4; i++) {
        ai[i] = As[4 * ty + i];
        ai[4 + i] = As[64 + 4 * ty + i];
    }
    #pragma unroll
    for (int j = 0; j < 4; j++) {
        bj[j] = Bs[4 * tx + j];
        bj[4 + j] = Bs[64 + 4 * tx + j];
    }

    #pragma unroll
    for (int i = 0; i < 8; i++) {
        int m = m0 + ((i < 4) ? (4 * ty + i) : (64 + 4 * ty + (i - 4)));
        float4 r0, r1;
        r0.x = __builtin_amdgcn_exp2f(fmaf(s, acc[i][0], ai[i] + bj[0]));
        r0.y = __builtin_amdgcn_exp2f(fmaf(s, acc[i][1], ai[i] + bj[1]));
        r0.z = __builtin_amdgcn_exp2f(fmaf(s, acc[i][2], ai[i] + bj[2]));
        r0.w = __builtin_amdgcn_exp2f(fmaf(s, acc[i][3], ai[i] + bj[3]));
        r1.x = __builtin_amdgcn_exp2f(fmaf(s, acc[i][4], ai[i] + bj[4]));
        r1.y = __builtin_amdgcn_exp2f(fmaf(s, acc[i][5], ai[i] + bj[5]));
        r1.z = __builtin_amdgcn_exp2f(fmaf(s, acc[i][6], ai[i] + bj[6]));
        r1.w = __builtin_amdgcn_exp2f(fmaf(s, acc[i][7], ai[i] + bj[7]));
        float* orow = out + (size_t)m * NROWS + n0;
        *(float4*)&orow[4 * tx] = r0;
        *(float4*)&orow[64 + 4 * tx] = r1;
    }
}

extern "C" void kernel_launch(void* const* d_in, const int* in_sizes, int n_in,
                              void* d_out, int out_size, void* d_ws, size_t ws_size,
                              hipStream_t stream) {
    const float* cent = (const float*)d_in[0];
    const float* x    = (const float*)d_in[1];
    const float* W1   = (const float*)d_in[2];
    const float* W2   = (const float*)d_in[3];
    const float* b2   = (const float*)d_in[4];
    float* out = (float*)d_out;

    float* ws   = (float*)d_ws;
    float* sums = ws;            // 2 floats (zeroed below)
    float* loc  = ws + 64;       // 4096*32 floats
    float* A    = loc + NROWS * DIMS;  // 8192 floats
    float* B    = A + MROWS;           // 4096 floats

    hipMemsetAsync(d_ws, 0, 8, stream);
    k_var<<<64, 256, 0, stream>>>(cent, sums);
    k_prep<<<48, 256, 0, stream>>>(cent, x, W1, W2, b2, sums, loc, A, B);
    k_pair<<<dim3(NROWS / TS, MROWS / TS), 256, 0, stream>>>(x, loc, A, B, sums, out);
}

// Round 3
// 180.063 us; speedup vs baseline: 1.1709x; 1.1709x over previous
//
#include <hip/hip_runtime.h>
#include <math.h>

#define DIMS 32
#define NROWS 4096
#define MROWS 8192
#define HID 100
#define TS 128
#define LDK 132  // padded K-major row stride (floats); 132*4=528 B, 16B-aligned

#define L2E 1.44269504088896340736f

typedef float f32x4 __attribute__((ext_vector_type(4)));

// ---------------- Kernel 1: partial sums of centroids + M = W2 @ W1 ----------------
// 8 blocks x 256. Block b: partial sum/sumsq of chunk b -> part[2b], part[2b+1].
// Block 0 additionally computes M[d][k] = sum_j W2[d*100+j] * W1[j*32+k]  (the two
// Linears collapse: there is no nonlinearity between them).
__global__ __launch_bounds__(256) void k_init(const float* __restrict__ c,
                                              const float* __restrict__ W1,
                                              const float* __restrict__ W2,
                                              float* __restrict__ part,
                                              float* __restrict__ Mmat) {
    int b = blockIdx.x, t = threadIdx.x;
    const float4* c4 = (const float4*)c;
    float s = 0.0f, q = 0.0f;
    #pragma unroll
    for (int i = 0; i < 16; i++) {
        float4 a = c4[b * 4096 + i * 256 + t];
        s += a.x + a.y + a.z + a.w;
        q += a.x * a.x + a.y * a.y + a.z * a.z + a.w * a.w;
    }
    #pragma unroll
    for (int off = 32; off > 0; off >>= 1) {
        s += __shfl_down(s, off);
        q += __shfl_down(q, off);
    }
    __shared__ float red[8];
    int lane = t & 63, wid = t >> 6;
    if (lane == 0) { red[wid] = s; red[4 + wid] = q; }
    __syncthreads();
    if (t == 0) {
        part[2 * b]     = red[0] + red[1] + red[2] + red[3];
        part[2 * b + 1] = red[4] + red[5] + red[6] + red[7];
    }
    if (b == 0) {
        __shared__ float w1s[HID * DIMS];
        __shared__ float w2s[DIMS * HID];
        for (int i = t; i < HID * DIMS; i += 256) { w1s[i] = W1[i]; w2s[i] = W2[i]; }
        __syncthreads();
        #pragma unroll
        for (int o = 0; o < 4; o++) {
            int id = o * 256 + t;
            int r = id >> 5, cc = id & 31;
            float a = 0.0f;
            for (int j = 0; j < HID; j++) a += w2s[r * HID + j] * w1s[j * DIMS + cc];
            Mmat[id] = a;
        }
    }
}

__device__ __forceinline__ void load_var(const float* part, float& iv, float& var) {
    float S = 0.0f, Q = 0.0f;
    #pragma unroll
    for (int i = 0; i < 8; i++) { S += part[2 * i]; Q += part[2 * i + 1]; }
    const float cnt = (float)(NROWS * DIMS);
    var = (Q - S * S / cnt) / (cnt - 1.0f);
    iv = 1.0f / var;
}

__device__ __forceinline__ float tanh_fast(float x) {
    float xc = fminf(fmaxf(x, -10.0f), 10.0f);
    float e = __builtin_amdgcn_exp2f(xc * (2.0f * L2E));  // e^(2x)
    return (e - 1.0f) * __builtin_amdgcn_rcpf(e + 1.0f);
}

// ---------------- Kernel 2: loc rows + B_n, and A_m ----------------
// blocks 0..15  : loc (4096 rows, 1 thread/row) via collapsed M
// blocks 16..47 : A   (8192 rows, 1 thread/row)
__global__ __launch_bounds__(256) void k_prep(const float* __restrict__ cent,
                                              const float* __restrict__ x,
                                              const float* __restrict__ b2,
                                              const float* __restrict__ part,
                                              const float* __restrict__ Mmat,
                                              float* __restrict__ loc,
                                              float* __restrict__ A,
                                              float* __restrict__ B) {
    float iv, var;
    load_var(part, iv, var);
    const float hv = -0.5f * L2E * iv;
    int t = threadIdx.x;

    if (blockIdx.x < 16) {
        __shared__ __align__(16) float ms[DIMS * DIMS];
        __shared__ float b2s[DIMS];
        for (int i = t; i < DIMS * DIMS; i += 256) ms[i] = Mmat[i];
        if (t < DIMS) b2s[t] = b2[t];
        __syncthreads();

        int n = blockIdx.x * 256 + t;  // 0..4095
        float c[DIMS];
        const float4* cr = (const float4*)(cent + (size_t)n * DIMS);
        #pragma unroll
        for (int i = 0; i < 8; i++) {
            float4 v = cr[i];
            c[4 * i] = v.x; c[4 * i + 1] = v.y; c[4 * i + 2] = v.z; c[4 * i + 3] = v.w;
        }
        float lr[DIMS];
        float lsq = 0.0f;
        #pragma unroll
        for (int d = 0; d < DIMS; d++) {
            const float4* mr = (const float4*)&ms[d * DIMS];
            float a0 = 0.f, a1 = 0.f, a2 = 0.f, a3 = 0.f;
            #pragma unroll
            for (int kk = 0; kk < 8; kk++) {
                float4 m = mr[kk];
                a0 += c[4 * kk] * m.x;
                a1 += c[4 * kk + 1] * m.y;
                a2 += c[4 * kk + 2] * m.z;
                a3 += c[4 * kk + 3] * m.w;
            }
            float v = tanh_fast((a0 + a1) + (a2 + a3) + b2s[d]) * c[d];
            lr[d] = v;
            lsq += v * v;
        }
        float4* lo = (float4*)(loc + (size_t)n * DIMS);
        #pragma unroll
        for (int i = 0; i < 8; i++)
            lo[i] = make_float4(lr[4 * i], lr[4 * i + 1], lr[4 * i + 2], lr[4 * i + 3]);
        B[n] = hv * lsq;
    } else {
        int m = (blockIdx.x - 16) * 256 + t;  // 0..8191
        const float4* xr = (const float4*)(x + (size_t)m * DIMS);
        float xsq = 0.0f;
        #pragma unroll
        for (int i = 0; i < 8; i++) {
            float4 v = xr[i];
            xsq += v.x * v.x + v.y * v.y + v.z * v.z + v.w * v.w;
        }
        float C0 = -16.0f * log2f(2.0f * (float)M_PI * var);  // -0.5*D*log2(2*pi*var)
        A[m] = hv * xsq + C0;
    }
}

// ---------------- Kernel 3: pairwise exp tile ----------------
// out[m,n] = exp2(A_m + B_n + s*dot(loc_n, x_m)),  s = log2(e)/var
// 128x128 tile per block, 256 threads, 8x8 micro-tile, nontemporal stores.
__global__ __launch_bounds__(256) void k_pair(const float* __restrict__ x,
                                              const float* __restrict__ loc,
                                              const float* __restrict__ A,
                                              const float* __restrict__ B,
                                              const float* __restrict__ part,
                                              float* __restrict__ out) {
    __shared__ __align__(16) float xs[DIMS][LDK];  // [k][m_local]
    __shared__ __align__(16) float ls[DIMS][LDK];  // [k][n_local]
    __shared__ float As[TS];
    __shared__ float Bs[TS];

    float iv, var;
    load_var(part, iv, var);
    const float s = L2E * iv;

    int n0 = blockIdx.x * TS;
    int m0 = blockIdx.y * TS;
    int t = threadIdx.x;

    // Stage tiles, transposing to K-major. Each thread: one half-row (16 floats).
    {
        int ml = t >> 1;               // 0..127
        int kh = (t & 1) * 16;         // 0 or 16
        const float4* xr = (const float4*)(x + (size_t)(m0 + ml) * DIMS + kh);
        float4 v0 = xr[0], v1 = xr[1], v2 = xr[2], v3 = xr[3];
        float vv[16] = {v0.x, v0.y, v0.z, v0.w, v1.x, v1.y, v1.z, v1.w,
                        v2.x, v2.y, v2.z, v2.w, v3.x, v3.y, v3.z, v3.w};
        #pragma unroll
        for (int q = 0; q < 16; q++) xs[kh + q][ml] = vv[q];

        const float4* lr = (const float4*)(loc + (size_t)(n0 + ml) * DIMS + kh);
        float4 u0 = lr[0], u1 = lr[1], u2 = lr[2], u3 = lr[3];
        float uu[16] = {u0.x, u0.y, u0.z, u0.w, u1.x, u1.y, u1.z, u1.w,
                        u2.x, u2.y, u2.z, u2.w, u3.x, u3.y, u3.z, u3.w};
        #pragma unroll
        for (int q = 0; q < 16; q++) ls[kh + q][ml] = uu[q];
    }
    if (t < TS) As[t] = A[m0 + t];
    else        Bs[t - TS] = B[n0 + t - TS];
    __syncthreads();

    int tx = t & 15;   // n groups: n_local = 4*tx+j and 64+4*tx+j
    int ty = t >> 4;   // m groups: m_local = 4*ty+i and 64+4*ty+i

    float acc[8][8];
    #pragma unroll
    for (int i = 0; i < 8; i++)
        #pragma unroll
        for (int j = 0; j < 8; j++) acc[i][j] = 0.0f;

    #pragma unroll 4
    for (int k = 0; k < DIMS; k++) {
        float4 xa = *(const float4*)&xs[k][4 * ty];
        float4 xb = *(const float4*)&xs[k][64 + 4 * ty];
        float4 la = *(const float4*)&ls[k][4 * tx];
        float4 lb = *(const float4*)&ls[k][64 + 4 * tx];
        float xm[8] = {xa.x, xa.y, xa.z, xa.w, xb.x, xb.y, xb.z, xb.w};
        float ln[8] = {la.x, la.y, la.z, la.w, lb.x, lb.y, lb.z, lb.w};
        #pragma unroll
        for (int i = 0; i < 8; i++)
            #pragma unroll
            for (int j = 0; j < 8; j++)
                acc[i][j] += xm[i] * ln[j];
    }

    float ai[8], bj[8];
    #pragma unroll
    for (int i = 0; i < 4; i++) {
        ai[i] = As[4 * ty + i];
        ai[4 + i] = As[64 + 4 * ty + i];
    }
    #pragma unroll
    for (int j = 0; j < 4; j++) {
        bj[j] = Bs[4 * tx + j];
        bj[4 + j] = Bs[64 + 4 * tx + j];
    }

    #pragma unroll
    for (int i = 0; i < 8; i++) {
        int m = m0 + ((i < 4) ? (4 * ty + i) : (64 + 4 * ty + (i - 4)));
        f32x4 r0, r1;
        r0.x = __builtin_amdgcn_exp2f(fmaf(s, acc[i][0], ai[i] + bj[0]));
        r0.y = __builtin_amdgcn_exp2f(fmaf(s, acc[i][1], ai[i] + bj[1]));
        r0.z = __builtin_amdgcn_exp2f(fmaf(s, acc[i][2], ai[i] + bj[2]));
        r0.w = __builtin_amdgcn_exp2f(fmaf(s, acc[i][3], ai[i] + bj[3]));
        r1.x = __builtin_amdgcn_exp2f(fmaf(s, acc[i][4], ai[i] + bj[4]));
        r1.y = __builtin_amdgcn_exp2f(fmaf(s, acc[i][5], ai[i] + bj[5]));
        r1.z = __builtin_amdgcn_exp2f(fmaf(s, acc[i][6], ai[i] + bj[6]));
        r1.w = __builtin_amdgcn_exp2f(fmaf(s, acc[i][7], ai[i] + bj[7]));
        float* orow = out + (size_t)m * NROWS + n0;
        __builtin_nontemporal_store(r0, (f32x4*)&orow[4 * tx]);
        __builtin_nontemporal_store(r1, (f32x4*)&orow[64 + 4 * tx]);
    }
}

extern "C" void kernel_launch(void* const* d_in, const int* in_sizes, int n_in,
                              void* d_out, int out_size, void* d_ws, size_t ws_size,
                              hipStream_t stream) {
    const float* cent = (const float*)d_in[0];
    const float* x    = (const float*)d_in[1];
    const float* W1   = (const float*)d_in[2];
    const float* W2   = (const float*)d_in[3];
    const float* b2   = (const float*)d_in[4];
    float* out = (float*)d_out;

    float* ws   = (float*)d_ws;
    float* part = ws;                      // 16 floats (written by k_init)
    float* Mmat = ws + 64;                 // 1024 floats
    float* loc  = Mmat + 1024;             // 4096*32 floats
    float* A    = loc + NROWS * DIMS;      // 8192 floats
    float* B    = A + MROWS;               // 4096 floats

    k_init<<<8, 256, 0, stream>>>(cent, W1, W2, part, Mmat);
    k_prep<<<48, 256, 0, stream>>>(cent, x, b2, part, Mmat, loc, A, B);
    k_pair<<<dim3(NROWS / TS, MROWS / TS), 256, 0, stream>>>(x, loc, A, B, part, out);
}